// Round 3
// 1566.092 us; speedup vs baseline: 1.0767x; 1.0767x over previous
//
#include <hip/hip_runtime.h>

typedef unsigned short u16;
typedef unsigned int u32;
typedef unsigned long long u64;
typedef __bf16 bf16x8 __attribute__((ext_vector_type(8)));
typedef float f32x4 __attribute__((ext_vector_type(4)));

// ---- ws layout (bytes) ---- max touched = 155,197,440 <= proven 155,463,680
#define OFF_XPROJ 0ull                   // 2*256*64*2048 bf16 = 134217728
#define OFF_XBF   134217728ull           // 64*256*512 bf16 = 16777216   (gemm phase only)
#define OFF_WXBF  150994944ull           // 4096*512 bf16 = 4194304      (gemm phase only)
#define OFF_BIAS  155189248ull           // 4096 bf16 = 8192
#define OFF_HRING 134217728ull           // ALIASES xbf+wxbf: 2 dir * 160 slots * 64*512 bf16 = 20971520
#define NSLOT 160
#define RESET_D 8

struct WPtrs { const float* p[8]; };

__device__ __forceinline__ u16 f2bf(float f) {
    __bf16 h = (__bf16)f;
    return __builtin_bit_cast(u16, h);
}
__device__ __forceinline__ float bf2f(u16 u) {
    __bf16 h = __builtin_bit_cast(__bf16, u);
    return (float)h;
}
__device__ __forceinline__ u32 pack2(float a, float b) {
    return (u32)f2bf(a) | ((u32)f2bf(b) << 16);
}
__device__ __forceinline__ float sigf(float x) {
    return __builtin_amdgcn_rcpf(1.0f + __expf(-x));
}
__device__ __forceinline__ float tanhfast(float x) {
    float a = fabsf(x);
    float e = __expf(-2.0f * a);
    float t = (1.0f - e) * __builtin_amdgcn_rcpf(1.0f + e);
    return copysignf(t, x);
}
__device__ __forceinline__ bool is_canary(u64 v) {
    return ((u32)v == 0xFFFFFFFFu) | ((u32)(v >> 32) == 0xFFFFFFFFu);
}

// ---------- pack x fp32 -> bf16 ----------
__global__ void __launch_bounds__(256) pack_x(const float* __restrict__ x, u16* __restrict__ xbf) {
    int idx = blockIdx.x * 256 + threadIdx.x;
    int e = idx * 4;
    float4 v = *(const float4*)(x + e);
    xbf[e+0] = f2bf(v.x); xbf[e+1] = f2bf(v.y);
    xbf[e+2] = f2bf(v.z); xbf[e+3] = f2bf(v.w);
}

// ---------- pack Wx (W[:, :512]) fp32 -> bf16, layout [n=(d,g,j)][k] ----------
__global__ void __launch_bounds__(256) pack_w(WPtrs wp, u16* __restrict__ wxbf) {
    int idx = blockIdx.x * 256 + threadIdx.x;
    int e = idx * 4;
    int n = e >> 9;
    int k = e & 511;
    int j = n & 511, g = (n >> 9) & 3, d = n >> 11;
    const float* W = wp.p[d*4 + g];
    float4 v = *(const float4*)(W + j*1024 + k);
    wxbf[n*512 + k + 0] = f2bf(v.x); wxbf[n*512 + k + 1] = f2bf(v.y);
    wxbf[n*512 + k + 2] = f2bf(v.z); wxbf[n*512 + k + 3] = f2bf(v.w);
}

// ---------- pack bias (bf16) ----------
__global__ void __launch_bounds__(256) pack_bias(WPtrs bp, u16* __restrict__ biasws) {
    int idx = blockIdx.x * 256 + threadIdx.x;   // 0..4095
    int j = idx & 511, g = (idx >> 9) & 3, d = idx >> 11;
    biasws[idx] = f2bf(bp.p[d*4 + g][j]);
}

// ---------- init h ring: slot 0 per dir = h(0)=0, slots 1..159 = canary ----------
// Launched AFTER gemm_xproj (the ring aliases xbf/wxbf).
__global__ void __launch_bounds__(256) init_hring(u16* __restrict__ ring) {
    size_t idx = (size_t)blockIdx.x * 256 + threadIdx.x;   // 1,310,720 threads
    size_t byte = idx * 16;
    size_t seg = byte % 10485760ull;                        // per-dir: 160*65536
    uint4 v;
    if (seg < 65536ull) { v.x = 0u; v.y = 0u; v.z = 0u; v.w = 0u; }
    else                { v.x = ~0u; v.y = ~0u; v.z = ~0u; v.w = ~0u; }
    *(uint4*)((char*)ring + byte) = v;
}

// ---------- xproj GEMM: xproj[d][t][b][g*512+j] = x[b][t]·Wx^T + bias (bf16 out) ----------
__global__ void __launch_bounds__(256) gemm_xproj(const u16* __restrict__ xbf,
                                                  const u16* __restrict__ wxbf,
                                                  const u16* __restrict__ biasws,
                                                  u16* __restrict__ xproj) {
    __shared__ u16 A[64 * 264];
    int tid = threadIdx.x, w = tid >> 6, lane = tid & 63, q = lane >> 4, ln = lane & 15;
    int mb = blockIdx.x >> 6, nb = blockIdx.x & 63;
    int n = nb*64 + w*16 + ln;

    bf16x8 bfr[16];
    #pragma unroll
    for (int kk = 0; kk < 16; ++kk)
        bfr[kk] = *(const bf16x8*)(wxbf + n*512 + kk*32 + q*8);
    float bias = bf2f(biasws[n]);

    f32x4 acc[4] = {{0.f,0.f,0.f,0.f},{0.f,0.f,0.f,0.f},{0.f,0.f,0.f,0.f},{0.f,0.f,0.f,0.f}};
    const u16* Abase = xbf + (size_t)mb * 64 * 512;

    for (int half = 0; half < 2; ++half) {
        for (int it = 0; it < 8; ++it) {
            int idx = tid + it*256;
            int r = idx >> 5, c = idx & 31;
            *(uint4*)&A[r*264 + c*8] = *(const uint4*)(Abase + r*512 + half*256 + c*8);
        }
        __syncthreads();
        #pragma unroll
        for (int kk = 0; kk < 8; ++kk) {
            #pragma unroll
            for (int mt = 0; mt < 4; ++mt) {
                bf16x8 af = *(const bf16x8*)&A[(mt*16 + ln)*264 + kk*32 + q*8];
                acc[mt] = __builtin_amdgcn_mfma_f32_16x16x32_bf16(af, bfr[half*8 + kk], acc[mt], 0, 0, 0);
            }
        }
        __syncthreads();
    }

    int dd = n >> 11, gg = (n >> 9) & 3, jj = n & 511;
    #pragma unroll
    for (int mt = 0; mt < 4; ++mt) {
        #pragma unroll
        for (int r2 = 0; r2 < 4; ++r2) {
            int m = mb*64 + mt*16 + q*4 + r2;
            int t = m & 255, b = m >> 8;
            float v = acc[mt][r2] + bias;
            xproj[(size_t)((dd*256 + t)*64 + b) * 2048 + gg*512 + jj] = f2bf(v);
        }
    }
}

// ---------- recurrent kernel: 64 blocks = 2 dirs x 32 col-slices ----------
// Barrier-free ring: slot(s)=s%160 holds h(s). Each u64 transitions canary->data once
// per epoch (relaxed agent atomics; per-dword atomicity + dual-half canary check = torn-
// proof readiness flag). Producers canary-reset their own word in slot (s+9)%160 at step
// s; within a direction blocks drift <=1 step, so the 151-step ring margin is huge.
// LDS kept < 63488 B (round-0-proven) by staging K in two 32KB halves.
__global__ void __launch_bounds__(256) bilstm_rec(const u16* __restrict__ xproj,
                                                  u16* __restrict__ hring,
                                                  float* __restrict__ out,
                                                  WPtrs wp) {
    __shared__ u16 A[64 * 256];          // 32768 B; one K-half, XOR chunk-swizzled
    __shared__ float pre[4 * 64 * 17];   // 17408 B; raw MFMA gate sums
    // total static LDS = 50176 B

    int tid = threadIdx.x, w = tid >> 6, lane = tid & 63, q = lane >> 4, ln = lane & 15;
    int d = blockIdx.x >> 5, cb = blockIdx.x & 31, j0 = cb * 16;
    int b = tid >> 2, hc0 = (tid & 3) * 4;
    int col8h = tid & 63, rb = tid >> 7;
    bool phB = (tid & 64) != 0;          // this thread's 32 words belong to K-half B

    // Wh fragments: persistent in registers. Wave w = gate w; lane holds row j0+ln.
    const float* Wg = wp.p[d*4 + w];
    bf16x8 bfr[16];
    #pragma unroll
    for (int kk = 0; kk < 16; ++kk) {
        const float* src = Wg + (j0 + ln)*1024 + 512 + kk*32 + q*8;
        float4 v0 = *(const float4*)src;
        float4 v1 = *(const float4*)(src + 4);
        bf16x8 t;
        t[0]=(__bf16)v0.x; t[1]=(__bf16)v0.y; t[2]=(__bf16)v0.z; t[3]=(__bf16)v0.w;
        t[4]=(__bf16)v1.x; t[5]=(__bf16)v1.y; t[6]=(__bf16)v1.z; t[7]=(__bf16)v1.w;
        bfr[kk] = t;
    }

    float cre[4] = {0.f, 0.f, 0.f, 0.f};    // cell state (thread-private)

    // per-thread xproj register prefetch: exactly the 4 gate-u64s this thread consumes
    u64 xp4[4];
    {
        int t0 = d ? 255 : 0;
        const u16* xp_t = xproj + ((size_t)((d*256 + t0)*64 + b))*2048 + j0 + hc0;
        #pragma unroll
        for (int g = 0; g < 4; ++g) xp4[g] = *(const u64*)(xp_t + g*512);
    }

    for (int s = 0; s < 256; ++s) {
        int t_ = d ? (255 - s) : s;
        int sl = s;      if (sl >= NSLOT) sl -= NSLOT;
        int sw = s + 1;  if (sw >= NSLOT) sw -= NSLOT;
        int sr = s + 1 + RESET_D; if (sr >= NSLOT) sr -= NSLOT;
        const u64* hsrc = (const u64*)hring + ((size_t)(d*NSLOT + sl)) * 8192;

        // ---- poll + resolve h(s) fully into registers: thread owns u64-column
        //      (tid&127), rows it*2+(tid>>7). Sentinel spin, batch load, straggler retry.
        u64 vv[32];
        {
            u64 v0 = __hip_atomic_load(hsrc + tid, __ATOMIC_RELAXED, __HIP_MEMORY_SCOPE_AGENT);
            while (is_canary(v0)) {
                __builtin_amdgcn_s_sleep(1);
                v0 = __hip_atomic_load(hsrc + tid, __ATOMIC_RELAXED, __HIP_MEMORY_SCOPE_AGENT);
            }
            vv[0] = v0;
        }
        #pragma unroll
        for (int it = 1; it < 32; ++it)
            vv[it] = __hip_atomic_load(hsrc + it*256 + tid, __ATOMIC_RELAXED, __HIP_MEMORY_SCOPE_AGENT);
        u32 pend = 0;
        #pragma unroll
        for (int it = 1; it < 32; ++it)
            if (is_canary(vv[it])) pend |= (1u << it);
        while (__builtin_expect(pend != 0u, 0)) {
            __builtin_amdgcn_s_sleep(1);
            u32 np = 0;
            #pragma unroll
            for (int it = 1; it < 32; ++it)
                if (pend & (1u << it)) {
                    u64 v = __hip_atomic_load(hsrc + it*256 + tid, __ATOMIC_RELAXED, __HIP_MEMORY_SCOPE_AGENT);
                    if (is_canary(v)) np |= (1u << it);
                    else vv[it] = v;
                }
            pend = np;
        }

        f32x4 acc[4] = {{0.f,0.f,0.f,0.f},{0.f,0.f,0.f,0.f},{0.f,0.f,0.f,0.f},{0.f,0.f,0.f,0.f}};

        // ---- K-half A: stage (cols 0..63 -> k<256), then MFMA kk=0..7 ----
        if (!phB) {
            #pragma unroll
            for (int it = 0; it < 32; ++it) {
                int row = it*2 + rb;
                int off = row*512 + ((((col8h >> 1) ^ (row & 7)) << 4) | ((col8h & 1) << 3));
                *(u64*)((char*)A + off) = vv[it];
            }
        }
        __syncthreads();                          // s1: half-A staged (also: prev cell's pre-reads done)
        #pragma unroll
        for (int kk = 0; kk < 8; ++kk) {
            #pragma unroll
            for (int mt = 0; mt < 4; ++mt) {
                int row = mt*16 + ln;
                bf16x8 af = *(const bf16x8*)((const char*)A + row*512 + (((kk*4 + q) ^ (ln & 7)) << 4));
                acc[mt] = __builtin_amdgcn_mfma_f32_16x16x32_bf16(af, bfr[kk], acc[mt], 0, 0, 0);
            }
        }
        __syncthreads();                          // s2: half-A reads done

        // ---- K-half B: stage (cols 64..127 -> k>=256), then MFMA kk=8..15 ----
        if (phB) {
            #pragma unroll
            for (int it = 0; it < 32; ++it) {
                int row = it*2 + rb;
                int off = row*512 + ((((col8h >> 1) ^ (row & 7)) << 4) | ((col8h & 1) << 3));
                *(u64*)((char*)A + off) = vv[it];
            }
        }
        __syncthreads();                          // s3: half-B staged
        #pragma unroll
        for (int kk = 0; kk < 8; ++kk) {
            #pragma unroll
            for (int mt = 0; mt < 4; ++mt) {
                int row = mt*16 + ln;
                bf16x8 af = *(const bf16x8*)((const char*)A + row*512 + (((kk*4 + q) ^ (ln & 7)) << 4));
                acc[mt] = __builtin_amdgcn_mfma_f32_16x16x32_bf16(af, bfr[8 + kk], acc[mt], 0, 0, 0);
            }
        }

        // ---- stash raw gate sums for the cross-wave cell phase ----
        #pragma unroll
        for (int mt = 0; mt < 4; ++mt) {
            #pragma unroll
            for (int r2 = 0; r2 < 4; ++r2)
                pre[w*1088 + (mt*16 + q*4 + r2)*17 + ln] = acc[mt][r2];
        }
        __syncthreads();                          // s4: pre ready (implies all half-B reads done)

        // ---- cell elementwise: thread owns (b = tid>>2, hc0 = (tid&3)*4 .. +3) ----
        float h4[4];
        #pragma unroll
        for (int k = 0; k < 4; ++k) {
            int hc = hc0 + k;
            float fpre = pre[0*1088 + b*17 + hc] + bf2f((u16)(xp4[0] >> (16*k)));
            float ipre = pre[1*1088 + b*17 + hc] + bf2f((u16)(xp4[1] >> (16*k)));
            float opre = pre[2*1088 + b*17 + hc] + bf2f((u16)(xp4[2] >> (16*k)));
            float gpre = pre[3*1088 + b*17 + hc] + bf2f((u16)(xp4[3] >> (16*k)));
            float fg = sigf(fpre), ig = sigf(ipre), og = sigf(opre);
            float gg = tanhfast(gpre);
            float c = fg * cre[k] + ig * gg;
            cre[k] = c;
            h4[k] = og * tanhfast(c);
        }

        // ---- publish h(s+1), then canary-reset our word in slot (s+9)%160 ----
        int wi = (b*512 + j0 + hc0) >> 2;
        {
            u64* hdst = (u64*)hring + ((size_t)(d*NSLOT + sw)) * 8192;
            u64 hv = (u64)pack2(h4[0], h4[1]) | ((u64)pack2(h4[2], h4[3]) << 32);
            __hip_atomic_store(hdst + wi, hv, __ATOMIC_RELAXED, __HIP_MEMORY_SCOPE_AGENT);
            u64* hrst = (u64*)hring + ((size_t)(d*NSLOT + sr)) * 8192;
            __hip_atomic_store(hrst + wi, ~0ull, __ATOMIC_RELAXED, __HIP_MEMORY_SCOPE_AGENT);
        }

        // out store — off the protocol path; drains during next step's poll
        f32x4 o4 = { h4[0], h4[1], h4[2], h4[3] };
        __builtin_nontemporal_store(o4, (f32x4*)&out[(size_t)(t_*64 + b)*1024 + d*512 + j0 + hc0]);

        // prefetch next xproj quads into registers (consumed next cell phase)
        if (s + 1 < 256) {
            int tn = d ? (254 - s) : (s + 1);
            const u16* xp_t = xproj + ((size_t)((d*256 + tn)*64 + b))*2048 + j0 + hc0;
            #pragma unroll
            for (int g = 0; g < 4; ++g) xp4[g] = *(const u64*)(xp_t + g*512);
        }
        // next iteration's s1 barrier covers pre-read/A-write hazards
    }
}

extern "C" void kernel_launch(void* const* d_in, const int* in_sizes, int n_in,
                              void* d_out, int out_size, void* d_ws, size_t ws_size,
                              hipStream_t stream) {
    const float* x = (const float*)d_in[0];
    WPtrs wp, bp;
    for (int d = 0; d < 2; ++d) {
        for (int g = 0; g < 4; ++g) {
            wp.p[d*4 + g] = (const float*)d_in[1 + d*8 + g*2];
            bp.p[d*4 + g] = (const float*)d_in[2 + d*8 + g*2];
        }
    }
    char* ws = (char*)d_ws;
    u16* xproj    = (u16*)(ws + OFF_XPROJ);
    u16* xbf      = (u16*)(ws + OFF_XBF);
    u16* wxbf     = (u16*)(ws + OFF_WXBF);
    u16* biasw    = (u16*)(ws + OFF_BIAS);
    u16* hring    = (u16*)(ws + OFF_HRING);
    float* out = (float*)d_out;

    hipLaunchKernelGGL(pack_x, dim3(8192), dim3(256), 0, stream, x, xbf);
    hipLaunchKernelGGL(pack_w, dim3(2048), dim3(256), 0, stream, wp, wxbf);
    hipLaunchKernelGGL(pack_bias, dim3(16), dim3(256), 0, stream, bp, biasw);
    hipLaunchKernelGGL(gemm_xproj, dim3(16384), dim3(256), 0, stream,
                       (const u16*)xbf, (const u16*)wxbf, (const u16*)biasw, xproj);
    hipLaunchKernelGGL(init_hring, dim3(5120), dim3(256), 0, stream, hring);   // after gemm: aliases xbf/wxbf

    const u16* xproj_c = xproj;
    void* args[] = { (void*)&xproj_c, (void*)&hring, (void*)&out, (void*)&wp };
    hipError_t err = hipLaunchCooperativeKernel((const void*)bilstm_rec, dim3(64), dim3(256), args, 0, stream);
    if (err != hipSuccess) {
        // 64 blocks <= 256 CUs are always co-resident; plain launch is protocol-safe.
        hipLaunchKernelGGL(bilstm_rec, dim3(64), dim3(256), 0, stream,
                           xproj_c, hring, out, wp);
    }
}

// Round 4
// 1519.869 us; speedup vs baseline: 1.1095x; 1.0304x over previous
//
#include <hip/hip_runtime.h>

typedef unsigned short u16;
typedef unsigned int u32;
typedef unsigned long long u64;
typedef __bf16 bf16x8 __attribute__((ext_vector_type(8)));
typedef float f32x4 __attribute__((ext_vector_type(4)));

// ---- ws layout (bytes) ---- max touched = 155,197,440 <= proven 155,463,680
#define OFF_XPROJ 0ull                   // 2*256*64*2048 bf16 = 134217728
#define OFF_XBF   134217728ull           // 64*256*512 bf16 = 16777216   (gemm phase only)
#define OFF_WXBF  150994944ull           // 4096*512 bf16 = 4194304      (gemm phase only)
#define OFF_BIAS  155189248ull           // 4096 bf16 = 8192
#define OFF_HRING 134217728ull           // ALIASES xbf+wxbf: 2 dir * 160 slots * 64*512 bf16 = 20971520
#define NSLOT 160
#define RESET_D 64

struct WPtrs { const float* p[8]; };

__device__ __forceinline__ u16 f2bf(float f) {
    __bf16 h = (__bf16)f;
    return __builtin_bit_cast(u16, h);
}
__device__ __forceinline__ float bf2f(u16 u) {
    __bf16 h = __builtin_bit_cast(__bf16, u);
    return (float)h;
}
__device__ __forceinline__ u32 pack2(float a, float b) {
    return (u32)f2bf(a) | ((u32)f2bf(b) << 16);
}
__device__ __forceinline__ float sigf(float x) {
    return __builtin_amdgcn_rcpf(1.0f + __expf(-x));
}
__device__ __forceinline__ float tanhfast(float x) {
    float a = fabsf(x);
    float e = __expf(-2.0f * a);
    float t = (1.0f - e) * __builtin_amdgcn_rcpf(1.0f + e);
    return copysignf(t, x);
}
__device__ __forceinline__ bool is_canary(u64 v) {
    return ((u32)v == 0xFFFFFFFFu) | ((u32)(v >> 32) == 0xFFFFFFFFu);
}

// ---------- pack x fp32 -> bf16 ----------
__global__ void __launch_bounds__(256) pack_x(const float* __restrict__ x, u16* __restrict__ xbf) {
    int idx = blockIdx.x * 256 + threadIdx.x;
    int e = idx * 4;
    float4 v = *(const float4*)(x + e);
    xbf[e+0] = f2bf(v.x); xbf[e+1] = f2bf(v.y);
    xbf[e+2] = f2bf(v.z); xbf[e+3] = f2bf(v.w);
}

// ---------- pack Wx (W[:, :512]) fp32 -> bf16, layout [n=(d,g,j)][k] ----------
__global__ void __launch_bounds__(256) pack_w(WPtrs wp, u16* __restrict__ wxbf) {
    int idx = blockIdx.x * 256 + threadIdx.x;
    int e = idx * 4;
    int n = e >> 9;
    int k = e & 511;
    int j = n & 511, g = (n >> 9) & 3, d = n >> 11;
    const float* W = wp.p[d*4 + g];
    float4 v = *(const float4*)(W + j*1024 + k);
    wxbf[n*512 + k + 0] = f2bf(v.x); wxbf[n*512 + k + 1] = f2bf(v.y);
    wxbf[n*512 + k + 2] = f2bf(v.z); wxbf[n*512 + k + 3] = f2bf(v.w);
}

// ---------- pack bias (bf16) ----------
__global__ void __launch_bounds__(256) pack_bias(WPtrs bp, u16* __restrict__ biasws) {
    int idx = blockIdx.x * 256 + threadIdx.x;   // 0..4095
    int j = idx & 511, g = (idx >> 9) & 3, d = idx >> 11;
    biasws[idx] = f2bf(bp.p[d*4 + g][j]);
}

// ---------- init h ring: slot 0 per dir = h(0)=0, slots 1..159 = canary ----------
// Launched AFTER gemm_xproj (the ring aliases xbf/wxbf).
__global__ void __launch_bounds__(256) init_hring(u16* __restrict__ ring) {
    size_t idx = (size_t)blockIdx.x * 256 + threadIdx.x;   // 1,310,720 threads
    size_t byte = idx * 16;
    size_t seg = byte % 10485760ull;                        // per-dir: 160*65536
    uint4 v;
    if (seg < 65536ull) { v.x = 0u; v.y = 0u; v.z = 0u; v.w = 0u; }
    else                { v.x = ~0u; v.y = ~0u; v.z = ~0u; v.w = ~0u; }
    *(uint4*)((char*)ring + byte) = v;
}

// ---------- xproj GEMM ----------
// Output layout (gate-innermost): xproj[(d*256+t)*64 + b][j*4 + g]  (u16)
__global__ void __launch_bounds__(256) gemm_xproj(const u16* __restrict__ xbf,
                                                  const u16* __restrict__ wxbf,
                                                  const u16* __restrict__ biasws,
                                                  u16* __restrict__ xproj) {
    __shared__ u16 A[64 * 264];
    int tid = threadIdx.x, w = tid >> 6, lane = tid & 63, q = lane >> 4, ln = lane & 15;
    int mb = blockIdx.x >> 6, nb = blockIdx.x & 63;
    int n = nb*64 + w*16 + ln;

    bf16x8 bfr[16];
    #pragma unroll
    for (int kk = 0; kk < 16; ++kk)
        bfr[kk] = *(const bf16x8*)(wxbf + n*512 + kk*32 + q*8);
    float bias = bf2f(biasws[n]);

    f32x4 acc[4] = {{0.f,0.f,0.f,0.f},{0.f,0.f,0.f,0.f},{0.f,0.f,0.f,0.f},{0.f,0.f,0.f,0.f}};
    const u16* Abase = xbf + (size_t)mb * 64 * 512;

    for (int half = 0; half < 2; ++half) {
        for (int it = 0; it < 8; ++it) {
            int idx = tid + it*256;
            int r = idx >> 5, c = idx & 31;
            *(uint4*)&A[r*264 + c*8] = *(const uint4*)(Abase + r*512 + half*256 + c*8);
        }
        __syncthreads();
        #pragma unroll
        for (int kk = 0; kk < 8; ++kk) {
            #pragma unroll
            for (int mt = 0; mt < 4; ++mt) {
                bf16x8 af = *(const bf16x8*)&A[(mt*16 + ln)*264 + kk*32 + q*8];
                acc[mt] = __builtin_amdgcn_mfma_f32_16x16x32_bf16(af, bfr[half*8 + kk], acc[mt], 0, 0, 0);
            }
        }
        __syncthreads();
    }

    int dd = n >> 11, gg = (n >> 9) & 3, jj = n & 511;
    #pragma unroll
    for (int mt = 0; mt < 4; ++mt) {
        #pragma unroll
        for (int r2 = 0; r2 < 4; ++r2) {
            int m = mb*64 + mt*16 + q*4 + r2;
            int t = m & 255, b = m >> 8;
            float v = acc[mt][r2] + bias;
            xproj[(size_t)((dd*256 + t)*64 + b) * 2048 + jj*4 + gg] = f2bf(v);
        }
    }
}

// ---------- recurrent kernel: 64 blocks = 2 dirs x 32 col-slices ----------
// Wave-per-batch-tile structure: wave w owns batches w*16..w*16+15 and computes ALL 4
// gates for them (Wh for all gates = A-operand, persistent in 256 VGPRs). Each wave:
//  - polls/stages only ITS batches' h into a private 8KB LDS region (no cross-wave
//    sharing -> ZERO __syncthreads in the kernel),
//  - MFMA D[j][b] = mfma(Wh_frag, h_frag) so each lane ends with 4 gates x 4 j for one
//    batch -> cell phase fully in registers,
//  - publishes one u64 (4 consecutive j, bf16) per lane to the canary ring.
// Ring protocol as round 3 (write-once-per-epoch canary u64s, relaxed agent atomics),
// reset distance bumped to 64 slots for visibility margin.
__global__ void __launch_bounds__(256, 1) bilstm_rec(const u16* __restrict__ xproj,
                                                     u16* __restrict__ hring,
                                                     float* __restrict__ out,
                                                     WPtrs wp) {
    __shared__ u16 A[4 * 4096];          // 4 waves x (16 rows x 256 k x 2B) = 32768 B

    int tid = threadIdx.x, w = tid >> 6, l = tid & 63, q = l >> 4, ln = l & 15;
    int d = blockIdx.x >> 5, cb = blockIdx.x & 31, j0 = cb * 16;
    int b = w*16 + ln;                   // this lane's batch
    char* Aw = (char*)A + w * 8192;

    // A-operand fragments: Wh[j0+ln][k] for all 4 gates (lane&15 = j-row of A-frag).
    bf16x8 bfr[4][16];
    #pragma unroll
    for (int g = 0; g < 4; ++g) {
        const float* Wg = wp.p[d*4 + g];
        #pragma unroll
        for (int kk = 0; kk < 16; ++kk) {
            const float* src = Wg + (j0 + ln)*1024 + 512 + kk*32 + q*8;
            float4 v0 = *(const float4*)src;
            float4 v1 = *(const float4*)(src + 4);
            bf16x8 t;
            t[0]=(__bf16)v0.x; t[1]=(__bf16)v0.y; t[2]=(__bf16)v0.z; t[3]=(__bf16)v0.w;
            t[4]=(__bf16)v1.x; t[5]=(__bf16)v1.y; t[6]=(__bf16)v1.z; t[7]=(__bf16)v1.w;
            bfr[g][kk] = t;
        }
    }

    float cre[4] = {0.f, 0.f, 0.f, 0.f};    // cell state: (b, j0+q*4+r2), fixed per lane

    // xproj register prefetch: 4 gates x 4 j = 16 u16 = 2 uint4 (gate-innermost layout)
    uint4 xpa, xpb;
    {
        int t0 = d ? 255 : 0;
        const u16* p = xproj + ((size_t)((d*256 + t0)*64 + b))*2048 + (size_t)(j0 + q*4)*4;
        xpa = *(const uint4*)p;
        xpb = *(const uint4*)(p + 8);
    }

    for (int s = 0; s < 256; ++s) {
        int t_ = d ? (255 - s) : s;
        int sl = s;      if (sl >= NSLOT) sl -= NSLOT;
        int sw = s + 1;  if (sw >= NSLOT) sw -= NSLOT;
        int sr = s + 1 + RESET_D; if (sr >= NSLOT) sr -= NSLOT;
        const u64* hsrc = (const u64*)hring + (size_t)(d*NSLOT + sl) * 8192;

        // ---- poll + resolve this wave's h rows into registers ----
        // lane owns u64-cols {l, l+64} of rows w*16..w*16+15: vv[r*2+chalf].
        u64 vv[32];
        {
            u64 v0 = __hip_atomic_load(hsrc + (size_t)(w*16)*128 + l, __ATOMIC_RELAXED, __HIP_MEMORY_SCOPE_AGENT);
            while (is_canary(v0)) {
                __builtin_amdgcn_s_sleep(1);
                v0 = __hip_atomic_load(hsrc + (size_t)(w*16)*128 + l, __ATOMIC_RELAXED, __HIP_MEMORY_SCOPE_AGENT);
            }
            vv[0] = v0;
        }
        #pragma unroll
        for (int it = 1; it < 32; ++it)
            vv[it] = __hip_atomic_load(hsrc + (size_t)(w*16 + (it >> 1))*128 + l + (it & 1)*64,
                                       __ATOMIC_RELAXED, __HIP_MEMORY_SCOPE_AGENT);
        u32 pend = 0;
        #pragma unroll
        for (int it = 1; it < 32; ++it)
            if (is_canary(vv[it])) pend |= (1u << it);
        while (__builtin_expect(pend != 0u, 0)) {
            __builtin_amdgcn_s_sleep(1);
            u32 np = 0;
            #pragma unroll
            for (int it = 1; it < 32; ++it)
                if (pend & (1u << it)) {
                    u64 v = __hip_atomic_load(hsrc + (size_t)(w*16 + (it >> 1))*128 + l + (it & 1)*64,
                                              __ATOMIC_RELAXED, __HIP_MEMORY_SCOPE_AGENT);
                    if (is_canary(v)) np |= (1u << it);
                    else vv[it] = v;
                }
            pend = np;
        }

        f32x4 acc[4] = {{0.f,0.f,0.f,0.f},{0.f,0.f,0.f,0.f},{0.f,0.f,0.f,0.f},{0.f,0.f,0.f,0.f}};

        // ---- K-half 0: stage own rows, read h-frags, MFMA (wave-private; no barrier) ----
        #pragma unroll
        for (int r = 0; r < 16; ++r) {
            int off = r*512 + ((((l >> 1) ^ (r & 7)) << 4) | ((l & 1) << 3));
            *(u64*)(Aw + off) = vv[r*2 + 0];
        }
        {
            bf16x8 hf[8];
            #pragma unroll
            for (int kk = 0; kk < 8; ++kk)
                hf[kk] = *(const bf16x8*)(Aw + ln*512 + (((kk*4 + q) ^ (ln & 7)) << 4));
            #pragma unroll
            for (int kk = 0; kk < 8; ++kk) {
                #pragma unroll
                for (int g = 0; g < 4; ++g)
                    acc[g] = __builtin_amdgcn_mfma_f32_16x16x32_bf16(bfr[g][kk], hf[kk], acc[g], 0, 0, 0);
            }
        }

        // ---- K-half 1 (overwrites the same 8KB; compiler orders via lgkmcnt) ----
        #pragma unroll
        for (int r = 0; r < 16; ++r) {
            int off = r*512 + ((((l >> 1) ^ (r & 7)) << 4) | ((l & 1) << 3));
            *(u64*)(Aw + off) = vv[r*2 + 1];
        }
        {
            bf16x8 hf[8];
            #pragma unroll
            for (int kk = 0; kk < 8; ++kk)
                hf[kk] = *(const bf16x8*)(Aw + ln*512 + (((kk*4 + q) ^ (ln & 7)) << 4));
            #pragma unroll
            for (int kk = 0; kk < 8; ++kk) {
                #pragma unroll
                for (int g = 0; g < 4; ++g)
                    acc[g] = __builtin_amdgcn_mfma_f32_16x16x32_bf16(bfr[g][8 + kk], hf[kk], acc[g], 0, 0, 0);
            }
        }

        // ---- cell: all in registers. lane owns (b, j = j0 + q*4 + r2), r2=0..3 ----
        u32 xq[8];
        xq[0]=xpa.x; xq[1]=xpa.y; xq[2]=xpa.z; xq[3]=xpa.w;
        xq[4]=xpb.x; xq[5]=xpb.y; xq[6]=xpb.z; xq[7]=xpb.w;
        float h4[4];
        #pragma unroll
        for (int r2 = 0; r2 < 4; ++r2) {
            float fpre = acc[0][r2] + bf2f((u16)(xq[r2*2]     & 0xFFFFu));
            float ipre = acc[1][r2] + bf2f((u16)(xq[r2*2]     >> 16));
            float opre = acc[2][r2] + bf2f((u16)(xq[r2*2 + 1] & 0xFFFFu));
            float gpre = acc[3][r2] + bf2f((u16)(xq[r2*2 + 1] >> 16));
            float fg = sigf(fpre), ig = sigf(ipre), og = sigf(opre);
            float gg = tanhfast(gpre);
            float c = fg * cre[r2] + ig * gg;
            cre[r2] = c;
            h4[r2] = og * tanhfast(c);
        }

        // ---- publish h(s+1) (one u64: 4 consecutive j), canary-reset slot s+1+64 ----
        {
            int wi = b*128 + cb*4 + q;
            u64* hdst = (u64*)hring + (size_t)(d*NSLOT + sw) * 8192;
            u64 hv = (u64)pack2(h4[0], h4[1]) | ((u64)pack2(h4[2], h4[3]) << 32);
            __hip_atomic_store(hdst + wi, hv, __ATOMIC_RELAXED, __HIP_MEMORY_SCOPE_AGENT);
            u64* hrst = (u64*)hring + (size_t)(d*NSLOT + sr) * 8192;
            __hip_atomic_store(hrst + wi, ~0ull, __ATOMIC_RELAXED, __HIP_MEMORY_SCOPE_AGENT);
        }

        // out store — off the protocol path
        f32x4 o4 = { h4[0], h4[1], h4[2], h4[3] };
        __builtin_nontemporal_store(o4, (f32x4*)&out[(size_t)(t_*64 + b)*1024 + d*512 + j0 + q*4]);

        // prefetch next xproj quads
        if (s + 1 < 256) {
            int tn = d ? (254 - s) : (s + 1);
            const u16* p = xproj + ((size_t)((d*256 + tn)*64 + b))*2048 + (size_t)(j0 + q*4)*4;
            xpa = *(const uint4*)p;
            xpb = *(const uint4*)(p + 8);
        }
    }
}

extern "C" void kernel_launch(void* const* d_in, const int* in_sizes, int n_in,
                              void* d_out, int out_size, void* d_ws, size_t ws_size,
                              hipStream_t stream) {
    const float* x = (const float*)d_in[0];
    WPtrs wp, bp;
    for (int d = 0; d < 2; ++d) {
        for (int g = 0; g < 4; ++g) {
            wp.p[d*4 + g] = (const float*)d_in[1 + d*8 + g*2];
            bp.p[d*4 + g] = (const float*)d_in[2 + d*8 + g*2];
        }
    }
    char* ws = (char*)d_ws;
    u16* xproj    = (u16*)(ws + OFF_XPROJ);
    u16* xbf      = (u16*)(ws + OFF_XBF);
    u16* wxbf     = (u16*)(ws + OFF_WXBF);
    u16* biasw    = (u16*)(ws + OFF_BIAS);
    u16* hring    = (u16*)(ws + OFF_HRING);
    float* out = (float*)d_out;

    hipLaunchKernelGGL(pack_x, dim3(8192), dim3(256), 0, stream, x, xbf);
    hipLaunchKernelGGL(pack_w, dim3(2048), dim3(256), 0, stream, wp, wxbf);
    hipLaunchKernelGGL(pack_bias, dim3(16), dim3(256), 0, stream, bp, biasw);
    hipLaunchKernelGGL(gemm_xproj, dim3(16384), dim3(256), 0, stream,
                       (const u16*)xbf, (const u16*)wxbf, (const u16*)biasw, xproj);
    hipLaunchKernelGGL(init_hring, dim3(5120), dim3(256), 0, stream, hring);   // after gemm: aliases xbf/wxbf

    const u16* xproj_c = xproj;
    void* args[] = { (void*)&xproj_c, (void*)&hring, (void*)&out, (void*)&wp };
    hipError_t err = hipLaunchCooperativeKernel((const void*)bilstm_rec, dim3(64), dim3(256), args, 0, stream);
    if (err != hipSuccess) {
        // 64 blocks <= 256 CUs are always co-resident; plain launch is protocol-safe.
        hipLaunchKernelGGL(bilstm_rec, dim3(64), dim3(256), 0, stream,
                           xproj_c, hring, out, wp);
    }
}